// Round 4
// baseline (49.239 us; speedup 1.0000x reference)
//
#include <hip/hip_runtime.h>

// ---------------- problem constants ----------------
#define B_    8192
#define K_    784       // IN_DIM
#define KP    832       // K padded to 13*64
#define NKB   13        // K blocks of 64
#define RP    1024      // unique w1 rows = HIDDEN/CF
#define HID   4096
#define OD    10
#define TS2   10240     // OUT_DIM*HIDDEN/CF

#define NB_X  3328      // 8192*104/256
#define NB_S  416       // 1024*104/256
#define NB_V  40        // 10240/256

typedef __attribute__((ext_vector_type(8))) short  bf16x8;
typedef __attribute__((ext_vector_type(4))) short  short4v;
typedef __attribute__((ext_vector_type(4))) float  f32x4;

__device__ __forceinline__ unsigned short f2bf(float f) {
    unsigned u = __builtin_bit_cast(unsigned, f);
    u += 0x7fffu + ((u >> 16) & 1u);          // RNE
    return (unsigned short)(u >> 16);
}
__device__ __forceinline__ float bf2f(unsigned short h) {
    unsigned u = ((unsigned)h) << 16;
    return __builtin_bit_cast(float, u);
}

// ================= merged prep kernel =====================================
// blocks [0, NB_X)            : x -> bf16, padded + per-row swizzled
// blocks [NB_X, NB_X+NB_S)    : tile1 -> +/-1 bf16, padded + swizzled
// blocks [NB_X+NB_S, ...+NB_V): V[o][r] = sum_c a1[c] * w2[o, c*1024+r]
__global__ __launch_bounds__(256) void prep(
    const float* __restrict__ x, const int* __restrict__ t1,
    const int* __restrict__ t2, const float* __restrict__ a1,
    const float* __restrict__ a2,
    unsigned short* __restrict__ Xsw, unsigned short* __restrict__ Ssw,
    float* __restrict__ V)
{
    const int b = blockIdx.x;
    if (b < NB_X) {
        const int id = b * 256 + threadIdx.x;
        const int row = id / 104;
        const int rem = id - row * 104;
        const int kb = rem >> 3;
        const int s  = rem & 7;
        const int kk = kb * 64 + (s ^ (row & 7)) * 8;
        bf16x8 v;
        if (kk < K_) {
            const float* xp = x + (size_t)row * K_ + kk;
            f32x4 a = *(const f32x4*)xp;
            f32x4 c = *(const f32x4*)(xp + 4);
            v[0] = (short)f2bf(a.x); v[1] = (short)f2bf(a.y);
            v[2] = (short)f2bf(a.z); v[3] = (short)f2bf(a.w);
            v[4] = (short)f2bf(c.x); v[5] = (short)f2bf(c.y);
            v[6] = (short)f2bf(c.z); v[7] = (short)f2bf(c.w);
        } else {
            v = (bf16x8)0;
        }
        *(bf16x8*)(Xsw + (size_t)row * KP + kb * 64 + s * 8) = v;
    } else if (b < NB_X + NB_S) {
        const int id = (b - NB_X) * 256 + threadIdx.x;
        const int row = id / 104;
        const int rem = id - row * 104;
        const int kb = rem >> 3;
        const int s  = rem & 7;
        const int kk = kb * 64 + (s ^ (row & 7)) * 8;
        bf16x8 v;
        if (kk < K_) {
            const int* tp = t1 + (size_t)row * K_ + kk;
            #pragma unroll
            for (int e = 0; e < 8; ++e)
                v[e] = (short)(tp[e] ? 0x3F80 : 0xBF80);
        } else {
            v = (bf16x8)0;
        }
        *(bf16x8*)(Ssw + (size_t)row * KP + kb * 64 + s * 8) = v;
    } else {
        const int id = (b - NB_X - NB_S) * 256 + threadIdx.x;   // < 10240
        const int o = id >> 10;
        const int r = id & 1023;
        float v = 0.f;
        #pragma unroll
        for (int c = 0; c < 4; ++c) {
            const int idx = o * HID + c * RP + r;
            const int ch  = idx / TS2;
            const float w2v = a2[ch] * (float)(2 * t2[idx - ch * TS2] - 1);
            v = fmaf(a1[c], w2v, v);
        }
        V[id] = v;
    }
}

// ================= GEMM1: Hr = relu(X @ S^T) in bf16 ======================
// 2 waves/block (128 thr), wave tile 128x64, BK=64 double-buffered (64 KB),
// 512 blocks = 2/CU. Counted vmcnt + raw barriers (round-3 pipeline logic).
__global__ __launch_bounds__(128, 1) void gemm1(const unsigned short* __restrict__ Xsw,
                                                const unsigned short* __restrict__ Ssw,
                                                unsigned short* __restrict__ Hr) {
    __shared__ unsigned short Xs[2][128 * 64];   // A: 128 m-rows x 64 k  (32 KB)
    __shared__ unsigned short Ss[2][128 * 64];   // B: 128 n-rows x 64 k  (32 KB)

    const int tid  = threadIdx.x;
    const int lane = tid & 63;
    const int wv   = tid >> 6;                   // 0 or 1

    // bijective XCD-chunked swizzle: XCD k owns bm-tiles [8k, 8k+8) x all bn
    const int swz = (blockIdx.x & 7) * 64 + (blockIdx.x >> 3);
    const int bm  = (swz >> 3) * 128;
    const int bn  = (swz & 7) * 128;

    const int wc = wv * 64;                      // this wave's B-col base

    // staging role: wave0 stages A, wave1 stages B (16 x 1KB loads each)
    const unsigned short* gsrc = wv ? Ssw : Xsw;
    const int             gbase = wv ? bn : bm;
    unsigned short*       lbase = wv ? &Ss[0][0] : &Xs[0][0];

    const int srow   = lane >> 3;                // 0..7
    const int sinrow = (lane & 7) << 3;          // ushort offset in 128B row

    f32x4 acc[8][4] = {};

#define STAGE(KB, BUF)                                                          \
    do {                                                                        \
        _Pragma("unroll")                                                       \
        for (int i = 0; i < 16; ++i) {                                          \
            const int row = i * 8 + srow;        /* 0..127 */                   \
            const unsigned short* g =                                           \
                gsrc + (size_t)(gbase + row) * KP + (KB) * 64 + sinrow;         \
            __builtin_amdgcn_global_load_lds(                                   \
                (const __attribute__((address_space(1))) void*)g,               \
                (__attribute__((address_space(3))) void*)                       \
                    (lbase + (BUF) * 8192 + i * 512 + lane * 8),                \
                16, 0, 0);                                                      \
        }                                                                       \
    } while (0)

    STAGE(0, 0);                                 // prologue: 16 loads in flight

    for (int kb = 0; kb < NKB; ++kb) {
        const int cur = kb & 1;
        if (kb + 1 < NKB) {
            STAGE(kb + 1, cur ^ 1);              // +16 loads (32 outstanding)
            asm volatile("s_waitcnt vmcnt(16)" ::: "memory");  // tile kb landed
        } else {
            asm volatile("s_waitcnt vmcnt(0)" ::: "memory");
        }
        __builtin_amdgcn_s_barrier();            // raw: does NOT drain vmcnt
        __builtin_amdgcn_sched_barrier(0);

        #pragma unroll
        for (int ks = 0; ks < 2; ++ks) {
            bf16x8 af[8], bfr[4];
            const int t = ks * 4 + (lane >> 4);
            #pragma unroll
            for (int mi = 0; mi < 8; ++mi) {
                const int row = mi * 16 + (lane & 15);
                af[mi] = *(const bf16x8*)&Xs[cur][row * 64 + ((t ^ (row & 7)) << 3)];
            }
            #pragma unroll
            for (int ni = 0; ni < 4; ++ni) {
                const int row = wc + ni * 16 + (lane & 15);
                bfr[ni] = *(const bf16x8*)&Ss[cur][row * 64 + ((t ^ (row & 7)) << 3)];
            }
            #pragma unroll
            for (int mi = 0; mi < 8; ++mi)
                #pragma unroll
                for (int ni = 0; ni < 4; ++ni)
                    acc[mi][ni] = __builtin_amdgcn_mfma_f32_16x16x32_bf16(
                        af[mi], bfr[ni], acc[mi][ni], 0, 0, 0);
        }

        __builtin_amdgcn_sched_barrier(0);
        __builtin_amdgcn_s_barrier();            // all done reading cur buffer
    }
#undef STAGE

    // epilogue: relu -> bf16 -> Hr[8192][1024]
    #pragma unroll
    for (int mi = 0; mi < 8; ++mi) {
        #pragma unroll
        for (int ni = 0; ni < 4; ++ni) {
            const int col = bn + wc + ni * 16 + (lane & 15);
            #pragma unroll
            for (int r = 0; r < 4; ++r) {
                const int rowg = bm + mi * 16 + (lane >> 4) * 4 + r;
                Hr[(size_t)rowg * RP + col] = f2bf(fmaxf(acc[mi][ni][r], 0.f));
            }
        }
    }
}

// ================= GEMM2: out = Hr @ V^T  (2 rows per wave) ===============
__global__ __launch_bounds__(256) void gemm2(const unsigned short* __restrict__ Hr,
                                             const float* __restrict__ V,
                                             float* __restrict__ out) {
    __shared__ float Vl[OD * RP];                // 40 KB
    const int tid = threadIdx.x;
    for (int i = tid; i < OD * RP / 4; i += 256)
        ((f32x4*)Vl)[i] = ((const f32x4*)V)[i];
    __syncthreads();

    const int lane = tid & 63;
    const int wid  = tid >> 6;

    #pragma unroll
    for (int rr = 0; rr < 2; ++rr) {
        const int b = blockIdx.x * 8 + wid * 2 + rr;

        float acc[OD];
        #pragma unroll
        for (int o = 0; o < OD; ++o) acc[o] = 0.f;

        #pragma unroll
        for (int q = 0; q < 4; ++q) {
            const int r = q * 256 + lane * 4;
            short4v hv = *(const short4v*)&Hr[(size_t)b * RP + r];
            float h0 = bf2f((unsigned short)hv[0]);
            float h1 = bf2f((unsigned short)hv[1]);
            float h2 = bf2f((unsigned short)hv[2]);
            float h3 = bf2f((unsigned short)hv[3]);
            #pragma unroll
            for (int o = 0; o < OD; ++o) {
                f32x4 v = *(const f32x4*)&Vl[o * RP + r];
                acc[o] += h0 * v.x + h1 * v.y + h2 * v.z + h3 * v.w;
            }
        }
        #pragma unroll
        for (int m = 1; m < 64; m <<= 1)
            #pragma unroll
            for (int o = 0; o < OD; ++o) acc[o] += __shfl_xor(acc[o], m);
        if (lane == 0) {
            #pragma unroll
            for (int o = 0; o < OD; ++o) out[(size_t)b * OD + o] = acc[o];
        }
    }
}

// ================= fallback (round-1 f32 SIMT fused kernel) ================
#define BM 128
#define BN 128
#define BK 16
__global__ __launch_bounds__(256, 2) void fused_tilednn(
    const float* __restrict__ x, const int* __restrict__ tile1,
    const float* __restrict__ alphas1, const int* __restrict__ tile2,
    const float* __restrict__ alphas2, float* __restrict__ out)
{
    __shared__ float XsF[BK][BM];
    __shared__ float SsF[BK][BN];
    __shared__ float Vl[OD][BN];
    const int t = threadIdx.x, tx = t & 15, ty = t >> 4;
    const int bm = blockIdx.x * BM, bn = blockIdx.y * BN;
    for (int e = t; e < OD * BN; e += 256) {
        const int o = e / BN, rl = e - o * BN, rr = bn + rl;
        float v = 0.f;
        #pragma unroll
        for (int c = 0; c < 4; ++c) {
            const int idx = o * HID + c * RP + rr;
            const int ch = idx / TS2;
            v = fmaf(alphas1[c], alphas2[ch] * (float)(2 * tile2[idx - ch * TS2] - 1), v);
        }
        Vl[o][rl] = v;
    }
    float acc[8][8];
    #pragma unroll
    for (int i = 0; i < 8; ++i)
        #pragma unroll
        for (int j = 0; j < 8; ++j) acc[i][j] = 0.f;
    const int lr = t >> 1, lk = (t & 1) << 3;
    const float* xrow = x + (size_t)(bm + lr) * K_;
    const int* srow = tile1 + (size_t)(bn + lr) * K_;
    for (int k0 = 0; k0 < K_; k0 += BK) {
        __syncthreads();
        const float4 xa = *(const float4*)(xrow + k0 + lk);
        const float4 xb = *(const float4*)(xrow + k0 + lk + 4);
        const int4 sa = *(const int4*)(srow + k0 + lk);
        const int4 sb = *(const int4*)(srow + k0 + lk + 4);
        XsF[lk+0][lr]=xa.x; XsF[lk+1][lr]=xa.y; XsF[lk+2][lr]=xa.z; XsF[lk+3][lr]=xa.w;
        XsF[lk+4][lr]=xb.x; XsF[lk+5][lr]=xb.y; XsF[lk+6][lr]=xb.z; XsF[lk+7][lr]=xb.w;
        SsF[lk+0][lr]=(float)(2*sa.x-1); SsF[lk+1][lr]=(float)(2*sa.y-1);
        SsF[lk+2][lr]=(float)(2*sa.z-1); SsF[lk+3][lr]=(float)(2*sa.w-1);
        SsF[lk+4][lr]=(float)(2*sb.x-1); SsF[lk+5][lr]=(float)(2*sb.y-1);
        SsF[lk+6][lr]=(float)(2*sb.z-1); SsF[lk+7][lr]=(float)(2*sb.w-1);
        __syncthreads();
        #pragma unroll
        for (int k = 0; k < BK; ++k) {
            float av[8], bv[8];
            #pragma unroll
            for (int i = 0; i < 8; ++i) av[i] = XsF[k][ty*8+i];
            #pragma unroll
            for (int j = 0; j < 8; ++j) bv[j] = SsF[k][tx*8+j];
            #pragma unroll
            for (int i = 0; i < 8; ++i)
                #pragma unroll
                for (int j = 0; j < 8; ++j) acc[i][j] = fmaf(av[i], bv[j], acc[i][j]);
        }
    }
    #pragma unroll
    for (int i = 0; i < 8; ++i)
        #pragma unroll
        for (int j = 0; j < 8; ++j) acc[i][j] = fmaxf(acc[i][j], 0.f);
    #pragma unroll
    for (int o = 0; o < OD; ++o) {
        float vv[8];
        #pragma unroll
        for (int j = 0; j < 8; ++j) vv[j] = Vl[o][tx*8+j];
        float p[8];
        #pragma unroll
        for (int i = 0; i < 8; ++i) {
            float s = 0.f;
            #pragma unroll
            for (int j = 0; j < 8; ++j) s = fmaf(acc[i][j], vv[j], s);
            p[i] = s;
        }
        #pragma unroll
        for (int m = 8; m >= 1; m >>= 1)
            #pragma unroll
            for (int i = 0; i < 8; ++i) p[i] += __shfl_xor(p[i], m, 16);
        if (tx == 0) {
            #pragma unroll
            for (int i = 0; i < 8; ++i)
                atomicAdd(&out[(size_t)(bm + ty*8 + i) * OD + o], p[i]);
        }
    }
}

// ================= launch ==================================================
extern "C" void kernel_launch(void* const* d_in, const int* in_sizes, int n_in,
                              void* d_out, int out_size, void* d_ws, size_t ws_size,
                              hipStream_t stream) {
    const float* x       = (const float*)d_in[0];
    const int*   tile1   = (const int*)  d_in[1];
    const float* alphas1 = (const float*)d_in[2];
    const int*   tile2   = (const int*)  d_in[3];
    const float* alphas2 = (const float*)d_in[4];
    float*       out     = (float*)d_out;

    const size_t OFF_X = 0;                                   // 8192*832*2
    const size_t OFF_S = OFF_X + (size_t)B_ * KP * 2;
    const size_t OFF_V = OFF_S + (size_t)RP * KP * 2;
    const size_t OFF_H = OFF_V + (size_t)OD * RP * 4;
    const size_t NEED  = OFF_H + (size_t)B_ * RP * 2;         // ~30.7 MB

    if (ws_size < NEED) {
        hipMemsetAsync(out, 0, (size_t)out_size * sizeof(float), stream);
        dim3 grid(B_ / BM, RP / BN);
        fused_tilednn<<<grid, 256, 0, stream>>>(x, tile1, alphas1, tile2, alphas2, out);
        return;
    }

    unsigned short* Xsw = (unsigned short*)((char*)d_ws + OFF_X);
    unsigned short* Ssw = (unsigned short*)((char*)d_ws + OFF_S);
    float*          V   = (float*)((char*)d_ws + OFF_V);
    unsigned short* Hr  = (unsigned short*)((char*)d_ws + OFF_H);

    prep<<<NB_X + NB_S + NB_V, 256, 0, stream>>>(x, tile1, tile2, alphas1, alphas2,
                                                 Xsw, Ssw, V);
    gemm1<<<512, 128, 0, stream>>>(Xsw, Ssw, Hr);
    gemm2<<<B_ / 8, 256, 0, stream>>>(Hr, V, out);
}

// Round 5
// 38.605 us; speedup vs baseline: 1.2754x; 1.2754x over previous
//
#include <hip/hip_runtime.h>

// ---------------- problem constants ----------------
#define B_    8192
#define K_    784      // IN_DIM
#define KP    832      // K padded to 13*64
#define NKB   13       // K blocks of 64
#define RP    1024     // unique w1 rows = HIDDEN/CF
#define HID   4096
#define OD    10
#define TS2   10240    // OUT_DIM*HIDDEN/CF

#define NB_X  3328     // 8192*104/256
#define NB_S  416      // 1024*104/256
#define NB_F  64       // 16*1024/256  (Vfrag)

typedef __attribute__((ext_vector_type(8))) short  bf16x8;
typedef __attribute__((ext_vector_type(4))) float  f32x4;

__device__ __forceinline__ unsigned short f2bf(float f) {
    unsigned u = __builtin_bit_cast(unsigned, f);
    u += 0x7fffu + ((u >> 16) & 1u);          // RNE
    return (unsigned short)(u >> 16);
}

// ================= merged prep kernel =====================================
// blocks [0, NB_X)          : x -> bf16, padded + per-row swizzled
// blocks [NB_X, NB_X+NB_S)  : tile1 -> +/-1 bf16, padded + swizzled
// blocks [.., +NB_F)        : Vfrag (bf16, MFMA B-fragment order, o padded to 16)
//   Vfrag[(r>>5)*512 + (o + 16*((r>>3)&3))*8 + (r&7)] = sum_c a1[c]*w2[o, c*1024+r]
__global__ __launch_bounds__(256) void prep(
    const float* __restrict__ x, const int* __restrict__ t1,
    const int* __restrict__ t2, const float* __restrict__ a1,
    const float* __restrict__ a2,
    unsigned short* __restrict__ Xsw, unsigned short* __restrict__ Ssw,
    unsigned short* __restrict__ Vfrag)
{
    const int b = blockIdx.x;
    if (b < NB_X) {
        const int id = b * 256 + threadIdx.x;
        const int row = id / 104;
        const int rem = id - row * 104;
        const int kb = rem >> 3;
        const int s  = rem & 7;
        const int kk = kb * 64 + (s ^ (row & 7)) * 8;
        bf16x8 v;
        if (kk < K_) {
            const float* xp = x + (size_t)row * K_ + kk;
            f32x4 a = *(const f32x4*)xp;
            f32x4 c = *(const f32x4*)(xp + 4);
            v[0] = (short)f2bf(a.x); v[1] = (short)f2bf(a.y);
            v[2] = (short)f2bf(a.z); v[3] = (short)f2bf(a.w);
            v[4] = (short)f2bf(c.x); v[5] = (short)f2bf(c.y);
            v[6] = (short)f2bf(c.z); v[7] = (short)f2bf(c.w);
        } else {
            v = (bf16x8)0;
        }
        *(bf16x8*)(Xsw + (size_t)row * KP + kb * 64 + s * 8) = v;
    } else if (b < NB_X + NB_S) {
        const int id = (b - NB_X) * 256 + threadIdx.x;
        const int row = id / 104;
        const int rem = id - row * 104;
        const int kb = rem >> 3;
        const int s  = rem & 7;
        const int kk = kb * 64 + (s ^ (row & 7)) * 8;
        bf16x8 v;
        if (kk < K_) {
            const int* tp = t1 + (size_t)row * K_ + kk;
            #pragma unroll
            for (int e = 0; e < 8; ++e)
                v[e] = (short)(tp[e] ? 0x3F80 : 0xBF80);
        } else {
            v = (bf16x8)0;
        }
        *(bf16x8*)(Ssw + (size_t)row * KP + kb * 64 + s * 8) = v;
    } else {
        const int id = (b - NB_X - NB_S) * 256 + threadIdx.x;   // < 16384
        const int o = id >> 10;           // 0..15 (10..15 are zero pad)
        const int r = id & 1023;
        float v = 0.f;
        if (o < OD) {
            #pragma unroll
            for (int c = 0; c < 4; ++c) {
                const int idx = o * HID + c * RP + r;
                const int ch  = idx / TS2;
                const float w2v = a2[ch] * (float)(2 * t2[idx - ch * TS2] - 1);
                v = fmaf(a1[c], w2v, v);
            }
        }
        Vfrag[(r >> 5) * 512 + (o + 16 * ((r >> 3) & 3)) * 8 + (r & 7)] = f2bf(v);
    }
}

// ================= GEMM1 + fused layer 2 ==================================
// main loop: round-3 structure verbatim (4 waves 2x2, 64x64 wave tile, BK=64
// double-buffered, counted vmcnt + raw barriers, 512 blocks = 2/CU).
// epilogue: relu(acc) -> bf16 -> LDS, mini-GEMM vs Vfrag, atomicAdd to out.
__global__ __launch_bounds__(256) void gemm1(const unsigned short* __restrict__ Xsw,
                                             const unsigned short* __restrict__ Ssw,
                                             const unsigned short* __restrict__ Vfrag,
                                             float* __restrict__ out) {
    __shared__ unsigned short Xs[2][128 * 64];   // double-buffered, 64 KB total
    __shared__ unsigned short Ss[2][128 * 64];

    const int tid  = threadIdx.x;
    const int lane = tid & 63;
    const int wid  = tid >> 6;

    // bijective XCD-chunked swizzle: XCD k owns bm-tiles [8k, 8k+8) x all bn
    const int swz = (blockIdx.x & 7) * 64 + (blockIdx.x >> 3);
    const int bm  = (swz >> 3) * 128;
    const int bn  = (swz & 7) * 128;

    const int wr = (wid >> 1) * 64;
    const int wc = (wid & 1) * 64;

    const int srow   = lane >> 3;              // 0..7 rows per 1KB chunk
    const int sinrow = (lane & 7) << 3;        // ushort offset within 128B row

    f32x4 acc[4][4] = {};

#define STAGE(KB, BUF)                                                          \
    do {                                                                        \
        _Pragma("unroll")                                                       \
        for (int i = 0; i < 4; ++i) {                                           \
            const int offB = wid * 4096 + i * 1024;   /* bytes in 16KB tile */  \
            const int row  = (offB >> 7) + srow;                                \
            const unsigned short* ga =                                          \
                Xsw + (size_t)(bm + row) * KP + (KB) * 64 + sinrow;             \
            const unsigned short* gb =                                          \
                Ssw + (size_t)(bn + row) * KP + (KB) * 64 + sinrow;             \
            __builtin_amdgcn_global_load_lds(                                   \
                (const __attribute__((address_space(1))) void*)ga,              \
                (__attribute__((address_space(3))) void*)(&Xs[BUF][offB >> 1]), \
                16, 0, 0);                                                      \
            __builtin_amdgcn_global_load_lds(                                   \
                (const __attribute__((address_space(1))) void*)gb,              \
                (__attribute__((address_space(3))) void*)(&Ss[BUF][offB >> 1]), \
                16, 0, 0);                                                      \
        }                                                                       \
    } while (0)

    STAGE(0, 0);                               // prologue: 8 loads in flight

    for (int kb = 0; kb < NKB; ++kb) {
        const int cur = kb & 1;
        if (kb + 1 < NKB) {
            STAGE(kb + 1, cur ^ 1);            // next tile: +8 loads
            asm volatile("s_waitcnt vmcnt(8)" ::: "memory");   // tile kb landed
        } else {
            asm volatile("s_waitcnt vmcnt(0)" ::: "memory");
        }
        __builtin_amdgcn_s_barrier();          // raw: does NOT drain vmcnt
        __builtin_amdgcn_sched_barrier(0);

        #pragma unroll
        for (int ks = 0; ks < 2; ++ks) {
            bf16x8 af[4], bfr[4];
            const int t = ks * 4 + (lane >> 4);
            #pragma unroll
            for (int mi = 0; mi < 4; ++mi) {
                const int row = wr + mi * 16 + (lane & 15);
                af[mi] = *(const bf16x8*)&Xs[cur][row * 64 + ((t ^ (row & 7)) << 3)];
            }
            #pragma unroll
            for (int ni = 0; ni < 4; ++ni) {
                const int row = wc + ni * 16 + (lane & 15);
                bfr[ni] = *(const bf16x8*)&Ss[cur][row * 64 + ((t ^ (row & 7)) << 3)];
            }
            #pragma unroll
            for (int mi = 0; mi < 4; ++mi)
                #pragma unroll
                for (int ni = 0; ni < 4; ++ni)
                    acc[mi][ni] = __builtin_amdgcn_mfma_f32_16x16x32_bf16(
                        af[mi], bfr[ni], acc[mi][ni], 0, 0, 0);
        }

        __builtin_amdgcn_sched_barrier(0);
        __builtin_amdgcn_s_barrier();          // all done reading cur buffer
    }
#undef STAGE

    // ---- fused epilogue ----------------------------------------------------
    // 1) relu(acc) -> bf16 -> Hlds[128][128] (reuse Xs; col-slot XOR swizzle)
    unsigned short* Hlds = &Xs[0][0];          // 128*128 ushorts = 32 KB
    __syncthreads();                           // everyone done reading Xs
    #pragma unroll
    for (int mi = 0; mi < 4; ++mi) {
        #pragma unroll
        for (int ni = 0; ni < 4; ++ni) {
            const int col = wc + ni * 16 + (lane & 15);
            #pragma unroll
            for (int r = 0; r < 4; ++r) {
                const int row = wr + mi * 16 + (lane >> 4) * 4 + r;
                Hlds[row * 128 + ((((col >> 3) ^ (row & 7)) << 3) | (col & 7))]
                    = f2bf(fmaxf(acc[mi][ni][r], 0.f));
            }
        }
    }
    __syncthreads();

    // 2) P[128,16] = H_tile @ V_slice^T via 8 MFMAs; wave handles 2 m-frags
    const int kb0 = bn >> 5;                   // first 32-wide k-frag of this bn
    bf16x8 vb[4];
    #pragma unroll
    for (int kk = 0; kk < 4; ++kk)
        vb[kk] = *(const bf16x8*)&Vfrag[(kb0 + kk) * 512 + lane * 8];

    #pragma unroll
    for (int mf = 0; mf < 2; ++mf) {
        const int mloc = (wid * 2 + mf) * 16;  // m-frag base row (0..112)
        const int mrow = mloc + (lane & 15);
        f32x4 pac = {};
        #pragma unroll
        for (int kk = 0; kk < 4; ++kk) {
            const int slot = kk * 4 + (lane >> 4);
            bf16x8 ha = *(const bf16x8*)&Hlds[mrow * 128 + ((slot ^ (mrow & 7)) << 3)];
            pac = __builtin_amdgcn_mfma_f32_16x16x32_bf16(ha, vb[kk], pac, 0, 0, 0);
        }
        const int o = lane & 15;
        if (o < OD) {
            #pragma unroll
            for (int r = 0; r < 4; ++r) {
                const int rowg = bm + mloc + (lane >> 4) * 4 + r;
                atomicAdd(&out[(size_t)rowg * OD + o], pac[r]);
            }
        }
    }
}

// ================= fallback (round-1 f32 SIMT fused kernel) ================
#define BM 128
#define BN 128
#define BK 16
__global__ __launch_bounds__(256, 2) void fused_tilednn(
    const float* __restrict__ x, const int* __restrict__ tile1,
    const float* __restrict__ alphas1, const int* __restrict__ tile2,
    const float* __restrict__ alphas2, float* __restrict__ out)
{
    __shared__ float XsF[BK][BM];
    __shared__ float SsF[BK][BN];
    __shared__ float Vl[OD][BN];
    const int t = threadIdx.x, tx = t & 15, ty = t >> 4;
    const int bm = blockIdx.x * BM, bn = blockIdx.y * BN;
    for (int e = t; e < OD * BN; e += 256) {
        const int o = e / BN, rl = e - o * BN, rr = bn + rl;
        float v = 0.f;
        #pragma unroll
        for (int c = 0; c < 4; ++c) {
            const int idx = o * HID + c * RP + rr;
            const int ch = idx / TS2;
            v = fmaf(alphas1[c], alphas2[ch] * (float)(2 * tile2[idx - ch * TS2] - 1), v);
        }
        Vl[o][rl] = v;
    }
    float acc[8][8];
    #pragma unroll
    for (int i = 0; i < 8; ++i)
        #pragma unroll
        for (int j = 0; j < 8; ++j) acc[i][j] = 0.f;
    const int lr = t >> 1, lk = (t & 1) << 3;
    const float* xrow = x + (size_t)(bm + lr) * K_;
    const int* srow = tile1 + (size_t)(bn + lr) * K_;
    for (int k0 = 0; k0 < K_; k0 += BK) {
        __syncthreads();
        const float4 xa = *(const float4*)(xrow + k0 + lk);
        const float4 xb = *(const float4*)(xrow + k0 + lk + 4);
        const int4 sa = *(const int4*)(srow + k0 + lk);
        const int4 sb = *(const int4*)(srow + k0 + lk + 4);
        XsF[lk+0][lr]=xa.x; XsF[lk+1][lr]=xa.y; XsF[lk+2][lr]=xa.z; XsF[lk+3][lr]=xa.w;
        XsF[lk+4][lr]=xb.x; XsF[lk+5][lr]=xb.y; XsF[lk+6][lr]=xb.z; XsF[lk+7][lr]=xb.w;
        SsF[lk+0][lr]=(float)(2*sa.x-1); SsF[lk+1][lr]=(float)(2*sa.y-1);
        SsF[lk+2][lr]=(float)(2*sa.z-1); SsF[lk+3][lr]=(float)(2*sa.w-1);
        SsF[lk+4][lr]=(float)(2*sb.x-1); SsF[lk+5][lr]=(float)(2*sb.y-1);
        SsF[lk+6][lr]=(float)(2*sb.z-1); SsF[lk+7][lr]=(float)(2*sb.w-1);
        __syncthreads();
        #pragma unroll
        for (int k = 0; k < BK; ++k) {
            float av[8], bv[8];
            #pragma unroll
            for (int i = 0; i < 8; ++i) av[i] = XsF[k][ty*8+i];
            #pragma unroll
            for (int j = 0; j < 8; ++j) bv[j] = SsF[k][tx*8+j];
            #pragma unroll
            for (int i = 0; i < 8; ++i)
                #pragma unroll
                for (int j = 0; j < 8; ++j) acc[i][j] = fmaf(av[i], bv[j], acc[i][j]);
        }
    }
    #pragma unroll
    for (int i = 0; i < 8; ++i)
        #pragma unroll
        for (int j = 0; j < 8; ++j) acc[i][j] = fmaxf(acc[i][j], 0.f);
    #pragma unroll
    for (int o = 0; o < OD; ++o) {
        float vv[8];
        #pragma unroll
        for (int j = 0; j < 8; ++j) vv[j] = Vl[o][tx*8+j];
        float p[8];
        #pragma unroll
        for (int i = 0; i < 8; ++i) {
            float s = 0.f;
            #pragma unroll
            for (int j = 0; j < 8; ++j) s = fmaf(acc[i][j], vv[j], s);
            p[i] = s;
        }
        #pragma unroll
        for (int m = 8; m >= 1; m >>= 1)
            #pragma unroll
            for (int i = 0; i < 8; ++i) p[i] += __shfl_xor(p[i], m, 16);
        if (tx == 0) {
            #pragma unroll
            for (int i = 0; i < 8; ++i)
                atomicAdd(&out[(size_t)(bm + ty*8 + i) * OD + o], p[i]);
        }
    }
}

// ================= launch ==================================================
extern "C" void kernel_launch(void* const* d_in, const int* in_sizes, int n_in,
                              void* d_out, int out_size, void* d_ws, size_t ws_size,
                              hipStream_t stream) {
    const float* x       = (const float*)d_in[0];
    const int*   tile1   = (const int*)  d_in[1];
    const float* alphas1 = (const float*)d_in[2];
    const int*   tile2   = (const int*)  d_in[3];
    const float* alphas2 = (const float*)d_in[4];
    float*       out     = (float*)d_out;

    const size_t OFF_X = 0;                                   // 8192*832*2
    const size_t OFF_S = OFF_X + (size_t)B_ * KP * 2;         // + 1024*832*2
    const size_t OFF_F = OFF_S + (size_t)RP * KP * 2;         // + 16*1024*2
    const size_t NEED  = OFF_F + (size_t)16 * RP * 2;         // ~15.4 MB

    // out is accumulated with atomics -> zero it every call (in-graph ok)
    hipMemsetAsync(out, 0, (size_t)out_size * sizeof(float), stream);

    if (ws_size < NEED) {
        dim3 grid(B_ / BM, RP / BN);
        fused_tilednn<<<grid, 256, 0, stream>>>(x, tile1, alphas1, tile2, alphas2, out);
        return;
    }

    unsigned short* Xsw   = (unsigned short*)((char*)d_ws + OFF_X);
    unsigned short* Ssw   = (unsigned short*)((char*)d_ws + OFF_S);
    unsigned short* Vfrag = (unsigned short*)((char*)d_ws + OFF_F);

    prep<<<NB_X + NB_S + NB_F, 256, 0, stream>>>(x, tile1, tile2, alphas1, alphas2,
                                                 Xsw, Ssw, Vfrag);
    gemm1<<<512, 256, 0, stream>>>(Xsw, Ssw, Vfrag, out);
}

// Round 6
// 34.453 us; speedup vs baseline: 1.4292x; 1.1205x over previous
//
#include <hip/hip_runtime.h>

// ---------------- problem constants ----------------
#define B_    8192
#define K_    784      // IN_DIM
#define KP    832      // K padded to 13*64
#define NKB   13       // K blocks of 64
#define RP    1024     // unique w1 rows = HIDDEN/CF
#define HID   4096
#define OD    10
#define TS2   10240    // OUT_DIM*HIDDEN/CF

#define NB_X  3328     // 8192*104/256
#define NB_S  416      // 1024*104/256
#define NB_F  64       // 16*1024/256  (Vfrag)
#define NB_Z  80       // 80*256*4 = 81920 floats of out zeroing

typedef __attribute__((ext_vector_type(8))) short  bf16x8;
typedef __attribute__((ext_vector_type(4))) float  f32x4;

__device__ __forceinline__ unsigned short f2bf(float f) {
    unsigned u = __builtin_bit_cast(unsigned, f);
    u += 0x7fffu + ((u >> 16) & 1u);          // RNE
    return (unsigned short)(u >> 16);
}

// ================= merged prep kernel =====================================
// blocks [0, NB_X)          : x -> bf16, padded + per-row swizzled
// blocks [NB_X, +NB_S)      : tile1 -> +/-1 bf16, padded + swizzled
// blocks [.., +NB_F)        : Vfrag (bf16, MFMA B-fragment order, o pad to 16)
// blocks [.., +NB_Z)        : zero out[] (replaces hipMemsetAsync dispatch)
__global__ __launch_bounds__(256) void prep(
    const float* __restrict__ x, const int* __restrict__ t1,
    const int* __restrict__ t2, const float* __restrict__ a1,
    const float* __restrict__ a2,
    unsigned short* __restrict__ Xsw, unsigned short* __restrict__ Ssw,
    unsigned short* __restrict__ Vfrag, float* __restrict__ out)
{
    const int b = blockIdx.x;
    if (b < NB_X) {
        const int id = b * 256 + threadIdx.x;
        const int row = id / 104;
        const int rem = id - row * 104;
        const int kb = rem >> 3;
        const int s  = rem & 7;
        const int kk = kb * 64 + (s ^ (row & 7)) * 8;
        bf16x8 v;
        if (kk < K_) {
            const float* xp = x + (size_t)row * K_ + kk;
            f32x4 a = *(const f32x4*)xp;
            f32x4 c = *(const f32x4*)(xp + 4);
            v[0] = (short)f2bf(a.x); v[1] = (short)f2bf(a.y);
            v[2] = (short)f2bf(a.z); v[3] = (short)f2bf(a.w);
            v[4] = (short)f2bf(c.x); v[5] = (short)f2bf(c.y);
            v[6] = (short)f2bf(c.z); v[7] = (short)f2bf(c.w);
        } else {
            v = (bf16x8)0;
        }
        *(bf16x8*)(Xsw + (size_t)row * KP + kb * 64 + s * 8) = v;
    } else if (b < NB_X + NB_S) {
        const int id = (b - NB_X) * 256 + threadIdx.x;
        const int row = id / 104;
        const int rem = id - row * 104;
        const int kb = rem >> 3;
        const int s  = rem & 7;
        const int kk = kb * 64 + (s ^ (row & 7)) * 8;
        bf16x8 v;
        if (kk < K_) {
            const int* tp = t1 + (size_t)row * K_ + kk;
            #pragma unroll
            for (int e = 0; e < 8; ++e)
                v[e] = (short)(tp[e] ? 0x3F80 : 0xBF80);
        } else {
            v = (bf16x8)0;
        }
        *(bf16x8*)(Ssw + (size_t)row * KP + kb * 64 + s * 8) = v;
    } else if (b < NB_X + NB_S + NB_F) {
        const int id = (b - NB_X - NB_S) * 256 + threadIdx.x;   // < 16384
        const int o = id >> 10;           // 0..15 (10..15 are zero pad)
        const int r = id & 1023;
        float v = 0.f;
        if (o < OD) {
            #pragma unroll
            for (int c = 0; c < 4; ++c) {
                const int idx = o * HID + c * RP + r;
                const int ch  = idx / TS2;
                const float w2v = a2[ch] * (float)(2 * t2[idx - ch * TS2] - 1);
                v = fmaf(a1[c], w2v, v);
            }
        }
        Vfrag[(r >> 5) * 512 + (o + 16 * ((r >> 3) & 3)) * 8 + (r & 7)] = f2bf(v);
    } else {
        const int id = (b - NB_X - NB_S - NB_F) * 256 + threadIdx.x;
        ((f32x4*)out)[id] = (f32x4){0.f, 0.f, 0.f, 0.f};
    }
}

// ================= GEMM1 + fused layer 2 ==================================
// m97 structure: 128x128 tile, BK=64 SINGLE-buffered (32 KB LDS), 4 waves 2x2,
// __syncthreads pipeline (implicit cross-block overlap at ~3 blocks/CU),
// global_load_lds w16, pre-swizzled operands. 512 blocks, XCD-chunked.
// epilogue: relu(acc) -> bf16 -> LDS overlay, mini-GEMM vs Vfrag, atomicAdd.
__global__ __launch_bounds__(256, 3) void gemm1(const unsigned short* __restrict__ Xsw,
                                                const unsigned short* __restrict__ Ssw,
                                                const unsigned short* __restrict__ Vfrag,
                                                float* __restrict__ out) {
    __shared__ unsigned short SH[2][128 * 64];   // [0]=A, [1]=B; 32 KB total

    const int tid  = threadIdx.x;
    const int lane = tid & 63;
    const int wid  = tid >> 6;

    // bijective XCD-chunked swizzle: XCD k owns bm-tiles [8k, 8k+8) x all bn
    const int swz = (blockIdx.x & 7) * 64 + (blockIdx.x >> 3);
    const int bm  = (swz >> 3) * 128;
    const int bn  = (swz & 7) * 128;

    const int wr = (wid >> 1) * 64;
    const int wc = (wid & 1) * 64;

    const int srow   = lane >> 3;              // 0..7 rows per 1KB chunk
    const int sinrow = (lane & 7) << 3;        // ushort offset within 128B row

    f32x4 acc[4][4] = {};

    for (int kb = 0; kb < NKB; ++kb) {
        // stage K-block kb (4 x A-chunk + 4 x B-chunk per wave, 1KB each)
        #pragma unroll
        for (int i = 0; i < 4; ++i) {
            const int offB = wid * 4096 + i * 1024;   // bytes within 16KB tile
            const int row  = (offB >> 7) + srow;
            const unsigned short* ga = Xsw + (size_t)(bm + row) * KP + kb * 64 + sinrow;
            const unsigned short* gb = Ssw + (size_t)(bn + row) * KP + kb * 64 + sinrow;
            __builtin_amdgcn_global_load_lds(
                (const __attribute__((address_space(1))) void*)ga,
                (__attribute__((address_space(3))) void*)(&SH[0][offB >> 1]),
                16, 0, 0);
            __builtin_amdgcn_global_load_lds(
                (const __attribute__((address_space(1))) void*)gb,
                (__attribute__((address_space(3))) void*)(&SH[1][offB >> 1]),
                16, 0, 0);
        }
        __syncthreads();                       // loads landed (vmcnt drain)

        #pragma unroll
        for (int ks = 0; ks < 2; ++ks) {
            bf16x8 af[4], bfr[4];
            const int t = ks * 4 + (lane >> 4);
            #pragma unroll
            for (int mi = 0; mi < 4; ++mi) {
                const int row = wr + mi * 16 + (lane & 15);
                af[mi] = *(const bf16x8*)&SH[0][row * 64 + ((t ^ (row & 7)) << 3)];
            }
            #pragma unroll
            for (int ni = 0; ni < 4; ++ni) {
                const int row = wc + ni * 16 + (lane & 15);
                bfr[ni] = *(const bf16x8*)&SH[1][row * 64 + ((t ^ (row & 7)) << 3)];
            }
            #pragma unroll
            for (int mi = 0; mi < 4; ++mi)
                #pragma unroll
                for (int ni = 0; ni < 4; ++ni)
                    acc[mi][ni] = __builtin_amdgcn_mfma_f32_16x16x32_bf16(
                        af[mi], bfr[ni], acc[mi][ni], 0, 0, 0);
        }
        __syncthreads();                       // all reads done before restage
    }

    // ---- fused epilogue ----------------------------------------------------
    // 1) relu(acc) -> bf16 -> Hlds[128][128] (overlay SH; col-slot XOR swizzle)
    unsigned short* Hlds = &SH[0][0];          // 128*128 ushorts = 32 KB
    #pragma unroll
    for (int mi = 0; mi < 4; ++mi) {
        #pragma unroll
        for (int ni = 0; ni < 4; ++ni) {
            const int col = wc + ni * 16 + (lane & 15);
            #pragma unroll
            for (int r = 0; r < 4; ++r) {
                const int row = wr + mi * 16 + (lane >> 4) * 4 + r;
                Hlds[row * 128 + ((((col >> 3) ^ (row & 7)) << 3) | (col & 7))]
                    = f2bf(fmaxf(acc[mi][ni][r], 0.f));
            }
        }
    }
    __syncthreads();

    // 2) P[128,16] = H_tile @ V_slice^T via 8 MFMAs; wave handles 2 m-frags
    const int kb0 = bn >> 5;                   // first 32-wide k-frag of this bn
    bf16x8 vb[4];
    #pragma unroll
    for (int kk = 0; kk < 4; ++kk)
        vb[kk] = *(const bf16x8*)&Vfrag[(kb0 + kk) * 512 + lane * 8];

    #pragma unroll
    for (int mf = 0; mf < 2; ++mf) {
        const int mloc = (wid * 2 + mf) * 16;  // m-frag base row (0..112)
        const int mrow = mloc + (lane & 15);
        f32x4 pac = {};
        #pragma unroll
        for (int kk = 0; kk < 4; ++kk) {
            const int slot = kk * 4 + (lane >> 4);
            bf16x8 ha = *(const bf16x8*)&Hlds[mrow * 128 + ((slot ^ (mrow & 7)) << 3)];
            pac = __builtin_amdgcn_mfma_f32_16x16x32_bf16(ha, vb[kk], pac, 0, 0, 0);
        }
        const int o = lane & 15;
        if (o < OD) {
            #pragma unroll
            for (int r = 0; r < 4; ++r) {
                const int rowg = bm + mloc + (lane >> 4) * 4 + r;
                atomicAdd(&out[(size_t)rowg * OD + o], pac[r]);
            }
        }
    }
}

// ================= fallback (round-1 f32 SIMT fused kernel) ================
#define BM 128
#define BN 128
#define BK 16
__global__ __launch_bounds__(256, 2) void fused_tilednn(
    const float* __restrict__ x, const int* __restrict__ tile1,
    const float* __restrict__ alphas1, const int* __restrict__ tile2,
    const float* __restrict__ alphas2, float* __restrict__ out)
{
    __shared__ float XsF[BK][BM];
    __shared__ float SsF[BK][BN];
    __shared__ float Vl[OD][BN];
    const int t = threadIdx.x, tx = t & 15, ty = t >> 4;
    const int bm = blockIdx.x * BM, bn = blockIdx.y * BN;
    for (int e = t; e < OD * BN; e += 256) {
        const int o = e / BN, rl = e - o * BN, rr = bn + rl;
        float v = 0.f;
        #pragma unroll
        for (int c = 0; c < 4; ++c) {
            const int idx = o * HID + c * RP + rr;
            const int ch = idx / TS2;
            v = fmaf(alphas1[c], alphas2[ch] * (float)(2 * tile2[idx - ch * TS2] - 1), v);
        }
        Vl[o][rl] = v;
    }
    float acc[8][8];
    #pragma unroll
    for (int i = 0; i < 8; ++i)
        #pragma unroll
        for (int j = 0; j < 8; ++j) acc[i][j] = 0.f;
    const int lr = t >> 1, lk = (t & 1) << 3;
    const float* xrow = x + (size_t)(bm + lr) * K_;
    const int* srow = tile1 + (size_t)(bn + lr) * K_;
    for (int k0 = 0; k0 < K_; k0 += BK) {
        __syncthreads();
        const float4 xa = *(const float4*)(xrow + k0 + lk);
        const float4 xb = *(const float4*)(xrow + k0 + lk + 4);
        const int4 sa = *(const int4*)(srow + k0 + lk);
        const int4 sb = *(const int4*)(srow + k0 + lk + 4);
        XsF[lk+0][lr]=xa.x; XsF[lk+1][lr]=xa.y; XsF[lk+2][lr]=xa.z; XsF[lk+3][lr]=xa.w;
        XsF[lk+4][lr]=xb.x; XsF[lk+5][lr]=xb.y; XsF[lk+6][lr]=xb.z; XsF[lk+7][lr]=xb.w;
        SsF[lk+0][lr]=(float)(2*sa.x-1); SsF[lk+1][lr]=(float)(2*sa.y-1);
        SsF[lk+2][lr]=(float)(2*sa.z-1); SsF[lk+3][lr]=(float)(2*sa.w-1);
        SsF[lk+4][lr]=(float)(2*sb.x-1); SsF[lk+5][lr]=(float)(2*sb.y-1);
        SsF[lk+6][lr]=(float)(2*sb.z-1); SsF[lk+7][lr]=(float)(2*sb.w-1);
        __syncthreads();
        #pragma unroll
        for (int k = 0; k < BK; ++k) {
            float av[8], bv[8];
            #pragma unroll
            for (int i = 0; i < 8; ++i) av[i] = XsF[k][ty*8+i];
            #pragma unroll
            for (int j = 0; j < 8; ++j) bv[j] = SsF[k][tx*8+j];
            #pragma unroll
            for (int i = 0; i < 8; ++i)
                #pragma unroll
                for (int j = 0; j < 8; ++j) acc[i][j] = fmaf(av[i], bv[j], acc[i][j]);
        }
    }
    #pragma unroll
    for (int i = 0; i < 8; ++i)
        #pragma unroll
        for (int j = 0; j < 8; ++j) acc[i][j] = fmaxf(acc[i][j], 0.f);
    #pragma unroll
    for (int o = 0; o < OD; ++o) {
        float vv[8];
        #pragma unroll
        for (int j = 0; j < 8; ++j) vv[j] = Vl[o][tx*8+j];
        float p[8];
        #pragma unroll
        for (int i = 0; i < 8; ++i) {
            float s = 0.f;
            #pragma unroll
            for (int j = 0; j < 8; ++j) s = fmaf(acc[i][j], vv[j], s);
            p[i] = s;
        }
        #pragma unroll
        for (int m = 8; m >= 1; m >>= 1)
            #pragma unroll
            for (int i = 0; i < 8; ++i) p[i] += __shfl_xor(p[i], m, 16);
        if (tx == 0) {
            #pragma unroll
            for (int i = 0; i < 8; ++i)
                atomicAdd(&out[(size_t)(bm + ty*8 + i) * OD + o], p[i]);
        }
    }
}

// ================= launch ==================================================
extern "C" void kernel_launch(void* const* d_in, const int* in_sizes, int n_in,
                              void* d_out, int out_size, void* d_ws, size_t ws_size,
                              hipStream_t stream) {
    const float* x       = (const float*)d_in[0];
    const int*   tile1   = (const int*)  d_in[1];
    const float* alphas1 = (const float*)d_in[2];
    const int*   tile2   = (const int*)  d_in[3];
    const float* alphas2 = (const float*)d_in[4];
    float*       out     = (float*)d_out;

    const size_t OFF_X = 0;                                   // 8192*832*2
    const size_t OFF_S = OFF_X + (size_t)B_ * KP * 2;         // + 1024*832*2
    const size_t OFF_F = OFF_S + (size_t)RP * KP * 2;         // + 16*1024*2
    const size_t NEED  = OFF_F + (size_t)16 * RP * 2;         // ~15.4 MB

    if (ws_size < NEED) {
        hipMemsetAsync(out, 0, (size_t)out_size * sizeof(float), stream);
        dim3 grid(B_ / BM, RP / BN);
        fused_tilednn<<<grid, 256, 0, stream>>>(x, tile1, alphas1, tile2, alphas2, out);
        return;
    }

    unsigned short* Xsw   = (unsigned short*)((char*)d_ws + OFF_X);
    unsigned short* Ssw   = (unsigned short*)((char*)d_ws + OFF_S);
    unsigned short* Vfrag = (unsigned short*)((char*)d_ws + OFF_F);

    prep<<<NB_X + NB_S + NB_F + NB_Z, 256, 0, stream>>>(
        x, tile1, tile2, alphas1, alphas2, Xsw, Ssw, Vfrag, out);
    gemm1<<<512, 256, 0, stream>>>(Xsw, Ssw, Vfrag, out);
}